// Round 1
// 1012.521 us; speedup vs baseline: 1.0106x; 1.0106x over previous
//
#include <hip/hip_runtime.h>
#include <cstdint>
#include <cmath>

// ---------------------------------------------------------------------------
// SimpleTransformerBlock on MI355X (gfx950)
// B=4, L=4096 -> 16384 tokens, D=1024, HEADS=16, HEAD_DIM=64
// Round 5: GEMM rewritten as 256x256 / 8-wave / 4-phase double-buffered
// schedule with counted vmcnt(4) (T3+T4), setprio around MFMA (T5),
// proven conflict-free LDS panel swizzle kept byte-identical (T2 already
// satisfied: measured 0 bank conflicts), bijective XCD swizzle (T1).
// ln/attn/cast kernels unchanged from round 4.
// ---------------------------------------------------------------------------

#define NTOK   16384
#define DMODEL 1024

typedef __bf16 bf16x8 __attribute__((ext_vector_type(8)));
typedef float  f32x4  __attribute__((ext_vector_type(4)));
typedef unsigned int __attribute__((address_space(1))) as1_uint;
typedef unsigned int __attribute__((address_space(3))) as3_uint;

__device__ __forceinline__ unsigned short f2bf(float f) {
    unsigned int u = __builtin_bit_cast(unsigned int, f);
    u += 0x7fffu + ((u >> 16) & 1u);          // round-to-nearest-even
    return (unsigned short)(u >> 16);
}
__device__ __forceinline__ float bf2f(unsigned short s) {
    unsigned int u = ((unsigned int)s) << 16;
    return __builtin_bit_cast(float, u);
}

// async global->LDS, 16 B per lane; LDS base wave-uniform (HW adds lane*16)
__device__ __forceinline__ void g2l16(const unsigned short* g, unsigned short* l) {
    __builtin_amdgcn_global_load_lds((const as1_uint*)g, (as3_uint*)l, 16, 0, 0);
}

__device__ __forceinline__ f32x4 mfma16(bf16x8 a, bf16x8 b, f32x4 c) {
    return __builtin_amdgcn_mfma_f32_16x16x32_bf16(a, b, c, 0, 0, 0);
}

// ---------------------------------------------------------------------------
// fp32 -> bf16 cast (weights)
// ---------------------------------------------------------------------------
__global__ __launch_bounds__(256) void cast_f32_bf16(
    const float4* __restrict__ in, ushort4* __restrict__ out, int n4) {
    int i = blockIdx.x * 256 + threadIdx.x;
    if (i < n4) {
        float4 v = in[i];
        ushort4 o;
        o.x = f2bf(v.x); o.y = f2bf(v.y); o.z = f2bf(v.z); o.w = f2bf(v.w);
        out[i] = o;
    }
}

// ---------------------------------------------------------------------------
// LayerNorm (fp32 in) -> bf16 out.  One block (256 thr) per token, D=1024.
// ---------------------------------------------------------------------------
__global__ __launch_bounds__(256) void ln_cast(
    const float* __restrict__ x, const float* __restrict__ w,
    const float* __restrict__ b, unsigned short* __restrict__ out) {
    int tok = blockIdx.x;
    int t   = threadIdx.x;
    float4 v = ((const float4*)x)[tok * 256 + t];
    float s  = v.x + v.y + v.z + v.w;
    float ss = v.x * v.x + v.y * v.y + v.z * v.z + v.w * v.w;
    #pragma unroll
    for (int off = 32; off > 0; off >>= 1) {
        s  += __shfl_down(s, off);
        ss += __shfl_down(ss, off);
    }
    __shared__ float red[8];
    int wave = t >> 6;
    if ((t & 63) == 0) { red[wave * 2] = s; red[wave * 2 + 1] = ss; }
    __syncthreads();
    s  = red[0] + red[2] + red[4] + red[6];
    ss = red[1] + red[3] + red[5] + red[7];
    float mu  = s * (1.0f / 1024.0f);
    float var = ss * (1.0f / 1024.0f) - mu * mu;
    float rs  = rsqrtf(var + 1e-5f);
    float4 wv = ((const float4*)w)[t];
    float4 bv = ((const float4*)b)[t];
    ushort4 o;
    o.x = f2bf((v.x - mu) * rs * wv.x + bv.x);
    o.y = f2bf((v.y - mu) * rs * wv.y + bv.y);
    o.z = f2bf((v.z - mu) * rs * wv.z + bv.z);
    o.w = f2bf((v.w - mu) * rs * wv.w + bv.w);
    ((ushort4*)out)[tok * 256 + t] = o;
}

// ---------------------------------------------------------------------------
// Per-token head-attention: qkv row [3][16][64] bf16 -> out row [16*64] bf16.
// ---------------------------------------------------------------------------
__global__ __launch_bounds__(256) void attn_heads(
    const unsigned short* __restrict__ qkv, unsigned short* __restrict__ out) {
    __shared__ float sQ[1024], sK[1024], sV[1024];
    __shared__ float sS[256];
    int tok = blockIdx.x;
    int t   = threadIdx.x;
    const unsigned short* base = qkv + (size_t)tok * 3072;
    for (int i = t; i < 1024; i += 256) {
        sQ[i] = bf2f(base[i]);
        sK[i] = bf2f(base[1024 + i]);
        sV[i] = bf2f(base[2048 + i]);
    }
    __syncthreads();
    {
        int h = t >> 4, g = t & 15;
        float s = 0.0f;
        #pragma unroll
        for (int d = 0; d < 64; ++d) s += sQ[h * 64 + d] * sK[g * 64 + d];
        sS[h * 16 + g] = s * 0.125f;
    }
    __syncthreads();
    if (t < 16) {
        float mx = -1e30f;
        for (int g = 0; g < 16; ++g) mx = fmaxf(mx, sS[t * 16 + g]);
        float sum = 0.0f;
        for (int g = 0; g < 16; ++g) {
            float e = expf(sS[t * 16 + g] - mx);
            sS[t * 16 + g] = e;
            sum += e;
        }
        float inv = 1.0f / sum;
        for (int g = 0; g < 16; ++g) sS[t * 16 + g] *= inv;
    }
    __syncthreads();
    #pragma unroll
    for (int j = 0; j < 4; ++j) {
        int o = t + 256 * j;
        int h = o >> 6, d = o & 63;
        float s = 0.0f;
        #pragma unroll
        for (int g = 0; g < 16; ++g) s += sS[h * 16 + g] * sV[g * 64 + d];
        out[(size_t)tok * 1024 + o] = f2bf(s);
    }
}

// ---------------------------------------------------------------------------
// bf16 GEMM:  C[M,N] = A[M,K] . W[N,K]^T  (+ bias, + epilogue)
//   EPI 0: bf16 = acc+bias   EPI 1: f32 = acc+bias+resid (may alias Cout)
//   EPI 2: bf16 = gelu_tanh(acc+bias)
//
// 256x256 tile, BK=64, 512 threads = 8 waves (2M x 4N), per-wave 128x64
// output (acc[8][4] of 16x16x32 mfma).  LDS: 2 buffers x (A 4 panels +
// B 4 panels), panel = row-major 128x32 bf16 with the round-3 proven
// conflict-free chunk swizzle: chunk at pos c of row r holds global chunk
// c ^ ((r>>1)&3); staged via pre-swizzled global source + linear
// global_load_lds dest (1 dwordx4 instr = 1 panel for 512 threads, wave w
// writes rows [w*16, w*16+16)).  128 KiB LDS -> 1 block/CU by design.
//
// Schedule per K-tile (4 phases), double-buffered, counted vmcnt:
//   ph0: read a[kh0][0..7] + b[kh0][0,1]; stage next A kh0; 16 mfma; bar
//   ph1: read b[kh0][2,3];  stage next B kh0; 16 mfma; vmcnt(4); bar
//   ph2: read a[kh1][0..7] + b[kh1][0,1]; stage next A kh1; 16 mfma; bar
//   ph3: read b[kh1][2,3];  stage next B kh1; 16 mfma; vmcnt(4); bar
// vmcnt(4) = 2 loads/phase x 2 phases distance: the 4 newest stage loads
// may remain in flight; everything older (the panels the NEXT reads need)
// is complete before the barrier releases.  Raw s_barrier (never
// __syncthreads) so the queue is never drained to 0 in the main loop.
// Tail K-tile: compute-only, single vmcnt(0) before the kh1 phases.
// Requires M%256==0, N%256==0, K%64==0.
// ---------------------------------------------------------------------------
#define BM 256
#define BN 256

#define READ_A(kh) { _Pragma("unroll")                                        \
    for (int mf = 0; mf < 8; ++mf)                                            \
        a[mf] = *(const bf16x8*)(lA + bo + (kh)*8192 + pA + mf*512 + roA); }
#define READ_B(kh, i0, i1) {                                                  \
    b[i0] = *(const bf16x8*)(lB + bo + (kh)*8192 + pB + (i0)*512 + roB);      \
    b[i1] = *(const bf16x8*)(lB + bo + (kh)*8192 + pB + (i1)*512 + roB); }
#define MFMA_BLK(i0, i1) {                                                    \
    __builtin_amdgcn_s_setprio(1);                                            \
    _Pragma("unroll")                                                         \
    for (int mf = 0; mf < 8; ++mf) {                                          \
        acc[mf][i0] = mfma16(a[mf], b[i0], acc[mf][i0]);                      \
        acc[mf][i1] = mfma16(a[mf], b[i1], acc[mf][i1]);                      \
    }                                                                         \
    __builtin_amdgcn_s_setprio(0); }

template <int EPI>
__global__ __launch_bounds__(512, 2) void gemm_bf16(
    const unsigned short* __restrict__ A, const unsigned short* __restrict__ W,
    const float* __restrict__ bias, const float* resid, void* Cout,
    int M, int N, int K) {
    // [buf][panel kh*2+half][128*32]; 64 KiB each, 128 KiB total
    __shared__ __align__(16) unsigned short sA[2][4][4096];
    __shared__ __align__(16) unsigned short sB[2][4][4096];
    unsigned short* const lA = &sA[0][0][0];
    unsigned short* const lB = &sB[0][0][0];

    const int t    = threadIdx.x;
    const int lane = t & 63;
    const int w    = t >> 6;
    const int wm   = w >> 2;        // 0..1
    const int wn   = w & 3;         // 0..3

    // ---- tile mapping: bijective XCD swizzle (m204), m-fastest so the 32
    // CUs of one XCD share one L2-hot W panel while streaming A m-tiles.
    const int gm = M >> 8, gn = N >> 8;
    const int nwg = gm * gn;
    int swz;
    {
        const int q = nwg >> 3, r = nwg & 7;
        const int xcd = blockIdx.x & 7, lid = blockIdx.x >> 3;
        swz = (xcd < r ? xcd * (q + 1) : r * (q + 1) + (xcd - r) * q) + lid;
    }
    const int m0 = (swz % gm) << 8;
    const int n0 = (swz / gm) << 8;
    (void)gn;

    // ---- staging source (per lane): wave w covers panel rows [w*16,w*16+16)
    // chunk cg = pos ^ ((row>>1)&3); with row = w*16 + (lane>>2) this is
    // (lane&3) ^ ((lane>>3)&3), independent of w (w*8 === 0 mod 4).
    const int srow = w * 16 + (lane >> 2);
    const int cg8  = ((lane & 3) ^ ((lane >> 3) & 3)) * 8;
    const unsigned short* gA0 = A + (size_t)(m0 +       srow) * K + cg8;
    const unsigned short* gA1 = A + (size_t)(m0 + 128 + srow) * K + cg8;
    const unsigned short* gB0 = W + (size_t)(n0 +       srow) * K + cg8;
    const unsigned short* gB1 = W + (size_t)(n0 + 128 + srow) * K + cg8;
    const int wst = w * 512;            // LDS dest offset within panel

    // ---- fragment read offsets (proven swizzle): retrieved chunk == fq
    const int fr   = lane & 15, fq = lane >> 4;
    const int csw8 = (fq ^ ((fr >> 1) & 3)) * 8;
    const int roA  = fr * 32 + csw8;                    // + mf*512, + kh*8192
    const int roB  = (wn & 1) * 2048 + fr * 32 + csw8;  // + nf*512, + kh*8192
    const int pA   = wm * 4096;                         // A panel: kh*2+wm
    const int pB   = (wn >> 1) * 4096;                  // B panel: kh*2+(wn>>1)

    f32x4 acc[8][4] = {};

    // ---- prologue: stage tile 0 into buf 0, kh0 panels first ----
    g2l16(gA0,      lA + 0 * 4096 + wst);   // kh0 mh0
    g2l16(gA1,      lA + 1 * 4096 + wst);   // kh0 mh1
    g2l16(gB0,      lB + 0 * 4096 + wst);   // kh0 nh0
    g2l16(gB1,      lB + 1 * 4096 + wst);   // kh0 nh1
    g2l16(gA0 + 32, lA + 2 * 4096 + wst);   // kh1 mh0
    g2l16(gA1 + 32, lA + 3 * 4096 + wst);   // kh1 mh1
    g2l16(gB0 + 32, lB + 2 * 4096 + wst);   // kh1 nh0
    g2l16(gB1 + 32, lB + 3 * 4096 + wst);   // kh1 nh1
    asm volatile("s_waitcnt vmcnt(4)" ::: "memory");   // kh0 panels landed
    __builtin_amdgcn_s_barrier();

    const int NT = K >> 6;
    for (int kt = 0; kt < NT - 1; ++kt) {
        const int bo = (kt & 1) << 14;      // compute buffer (ushort units)
        const int so = bo ^ 16384;          // stage buffer
        const size_t kg = (size_t)kt * 64 + 64;
        bf16x8 a[8], b[4];

        // ---- ph0
        READ_A(0); READ_B(0, 0, 1);
        g2l16(gA0 + kg, lA + so + wst);
        g2l16(gA1 + kg, lA + so + 4096 + wst);
        MFMA_BLK(0, 1);
        __builtin_amdgcn_s_barrier();
        // ---- ph1
        READ_B(0, 2, 3);
        g2l16(gB0 + kg, lB + so + wst);
        g2l16(gB1 + kg, lB + so + 4096 + wst);
        MFMA_BLK(2, 3);
        asm volatile("s_waitcnt vmcnt(4)" ::: "memory");  // kh1(cur) landed
        __builtin_amdgcn_s_barrier();
        // ---- ph2
        READ_A(1); READ_B(1, 0, 1);
        g2l16(gA0 + kg + 32, lA + so + 8192 + wst);
        g2l16(gA1 + kg + 32, lA + so + 8192 + 4096 + wst);
        MFMA_BLK(0, 1);
        __builtin_amdgcn_s_barrier();
        // ---- ph3
        READ_B(1, 2, 3);
        g2l16(gB0 + kg + 32, lB + so + 8192 + wst);
        g2l16(gB1 + kg + 32, lB + so + 8192 + 4096 + wst);
        MFMA_BLK(2, 3);
        asm volatile("s_waitcnt vmcnt(4)" ::: "memory");  // kh0(next) landed
        __builtin_amdgcn_s_barrier();
    }

    // ---- tail K-tile (no staging) ----
    {
        const int bo = ((NT - 1) & 1) << 14;
        bf16x8 a[8], b[4];
        READ_A(0); READ_B(0, 0, 1);
        MFMA_BLK(0, 1);
        __builtin_amdgcn_s_barrier();
        READ_B(0, 2, 3);
        MFMA_BLK(2, 3);
        asm volatile("s_waitcnt vmcnt(0)" ::: "memory");  // kh1 landed
        __builtin_amdgcn_s_barrier();
        READ_A(1); READ_B(1, 0, 1);
        MFMA_BLK(0, 1);
        READ_B(1, 2, 3);
        MFMA_BLK(2, 3);
    }

    // ---- epilogue: C/D layout col = lane&15, row = (lane>>4)*4 + e ----
    #pragma unroll
    for (int nf = 0; nf < 4; ++nf) {
        const int col = n0 + wn * 64 + nf * 16 + fr;
        const float bv = bias[col];
        #pragma unroll
        for (int mf = 0; mf < 8; ++mf) {
            const int rowb = m0 + wm * 128 + mf * 16 + fq * 4;
            #pragma unroll
            for (int e = 0; e < 4; ++e) {
                size_t idx = (size_t)(rowb + e) * N + col;
                float v = acc[mf][nf][e] + bv;
                if (EPI == 0) {
                    ((unsigned short*)Cout)[idx] = f2bf(v);
                } else if (EPI == 1) {
                    ((float*)Cout)[idx] = v + resid[idx];
                } else {
                    // tanh-form GELU: |err| < ~1e-3, far below bf16 noise
                    float s  = 0.7978845608f * (v + 0.044715f * v * v * v);
                    float e2 = __expf(2.0f * s);
                    float th = 1.0f - 2.0f / (e2 + 1.0f);
                    ((unsigned short*)Cout)[idx] = f2bf(0.5f * v * (1.0f + th));
                }
            }
        }
    }
}

#undef READ_A
#undef READ_B
#undef MFMA_BLK

// ---------------------------------------------------------------------------
// launch — chunked over token blocks sized to fit ws_size.
// ---------------------------------------------------------------------------
extern "C" void kernel_launch(void* const* d_in, const int* in_sizes, int n_in,
                              void* d_out, int out_size, void* d_ws, size_t ws_size,
                              hipStream_t stream) {
    const float* x      = (const float*)d_in[0];
    const float* qkv_w  = (const float*)d_in[1];
    const float* qkv_b  = (const float*)d_in[2];
    const float* proj_w = (const float*)d_in[3];
    const float* proj_b = (const float*)d_in[4];
    const float* ln1_w  = (const float*)d_in[5];
    const float* ln1_b  = (const float*)d_in[6];
    const float* ln2_w  = (const float*)d_in[7];
    const float* ln2_b  = (const float*)d_in[8];
    const float* mlp_w1 = (const float*)d_in[9];
    const float* mlp_b1 = (const float*)d_in[10];
    const float* mlp_w2 = (const float*)d_in[11];
    const float* mlp_b2 = (const float*)d_in[12];
    float* out = (float*)d_out;

    // persistent bf16 weights: 24 MB
    const size_t WB = 25165824;
    char* ws = (char*)d_ws;
    unsigned short* w_qkv  = (unsigned short*)(ws);              // [3072,1024]
    unsigned short* w_proj = (unsigned short*)(ws + 6291456);    // [1024,1024]
    unsigned short* w_m1   = (unsigned short*)(ws + 8388608);    // [4096,1024]
    unsigned short* w_m2   = (unsigned short*)(ws + 16777216);   // [1024,4096]

    // largest chunk T fitting:  WB + T*(2048 h + 2048 attn + 8192 qkv|m)
    int T = NTOK;
    while (T >= 256 && WB + (size_t)T * 12288 > ws_size) T >>= 1;
    if (T < 256) {
        hipMemcpyAsync(out, x, (size_t)NTOK * DMODEL * sizeof(float),
                       hipMemcpyDeviceToDevice, stream);
        return;
    }

    unsigned short* hbuf = (unsigned short*)(ws + WB);                     // T*2048 B
    unsigned short* abuf = (unsigned short*)(ws + WB + (size_t)T * 2048);  // T*2048 B
    unsigned short* qmbuf= (unsigned short*)(ws + WB + (size_t)T * 4096);  // T*8192 B

    cast_f32_bf16<<<3072, 256, 0, stream>>>((const float4*)qkv_w,  (ushort4*)w_qkv,  786432);
    cast_f32_bf16<<<1024, 256, 0, stream>>>((const float4*)proj_w, (ushort4*)w_proj, 262144);
    cast_f32_bf16<<<4096, 256, 0, stream>>>((const float4*)mlp_w1, (ushort4*)w_m1,   1048576);
    cast_f32_bf16<<<4096, 256, 0, stream>>>((const float4*)mlp_w2, (ushort4*)w_m2,   1048576);

    for (int tok0 = 0; tok0 < NTOK; tok0 += T) {
        const float* xc   = x   + (size_t)tok0 * DMODEL;
        float*       outc = out + (size_t)tok0 * DMODEL;
        const int my = T / BM;

        ln_cast<<<T, 256, 0, stream>>>(xc, ln1_w, ln1_b, hbuf);
        gemm_bf16<0><<<(3072 / BN) * my, 512, 0, stream>>>(
            hbuf, w_qkv, qkv_b, nullptr, qmbuf, T, 3072, 1024);
        attn_heads<<<T, 256, 0, stream>>>(qmbuf, abuf);
        gemm_bf16<1><<<(1024 / BN) * my, 512, 0, stream>>>(
            abuf, w_proj, proj_b, xc, (void*)outc, T, 1024, 1024);
        ln_cast<<<T, 256, 0, stream>>>(outc, ln2_w, ln2_b, hbuf);
        gemm_bf16<2><<<(4096 / BN) * my, 512, 0, stream>>>(
            hbuf, w_m1, mlp_b1, nullptr, qmbuf, T, 4096, 1024);
        gemm_bf16<1><<<(1024 / BN) * my, 512, 0, stream>>>(
            qmbuf, w_m2, mlp_b2, outc, (void*)outc, T, 1024, 4096);
    }
}

// Round 2
// 926.034 us; speedup vs baseline: 1.1049x; 1.0934x over previous
//
#include <hip/hip_runtime.h>
#include <cstdint>
#include <cmath>

// ---------------------------------------------------------------------------
// SimpleTransformerBlock on MI355X (gfx950)
// B=4, L=4096 -> 16384 tokens, D=1024, HEADS=16, HEAD_DIM=64
// Round 6: L2-cooperative super-tile mapping.  Key arithmetic: 256^2 tile @
// BK=64 = 128 FLOP/B -> needs ~19.5 TB/s staging feed at MFMA peak, which
// only L2 can supply.  Concurrent blocks on one XCD now form an 8m x 4n
// super-tile (32 blocks = 32 CUs): per K-tile the XCD fetches 8 A-panels +
// 4 B-panels (384 KiB) instead of 32 block-exclusive loads (2 MiB) -> 5.3x
// less L2-miss traffic.  4-phase counted-vmcnt schedule unchanged (round 5,
// harness-verified).  ln/attn/cast kernels unchanged.
// ---------------------------------------------------------------------------

#define NTOK   16384
#define DMODEL 1024

typedef __bf16 bf16x8 __attribute__((ext_vector_type(8)));
typedef float  f32x4  __attribute__((ext_vector_type(4)));
typedef unsigned int __attribute__((address_space(1))) as1_uint;
typedef unsigned int __attribute__((address_space(3))) as3_uint;

__device__ __forceinline__ unsigned short f2bf(float f) {
    unsigned int u = __builtin_bit_cast(unsigned int, f);
    u += 0x7fffu + ((u >> 16) & 1u);          // round-to-nearest-even
    return (unsigned short)(u >> 16);
}
__device__ __forceinline__ float bf2f(unsigned short s) {
    unsigned int u = ((unsigned int)s) << 16;
    return __builtin_bit_cast(float, u);
}

// async global->LDS, 16 B per lane; LDS base wave-uniform (HW adds lane*16)
__device__ __forceinline__ void g2l16(const unsigned short* g, unsigned short* l) {
    __builtin_amdgcn_global_load_lds((const as1_uint*)g, (as3_uint*)l, 16, 0, 0);
}

__device__ __forceinline__ f32x4 mfma16(bf16x8 a, bf16x8 b, f32x4 c) {
    return __builtin_amdgcn_mfma_f32_16x16x32_bf16(a, b, c, 0, 0, 0);
}

// ---------------------------------------------------------------------------
// fp32 -> bf16 cast (weights)
// ---------------------------------------------------------------------------
__global__ __launch_bounds__(256) void cast_f32_bf16(
    const float4* __restrict__ in, ushort4* __restrict__ out, int n4) {
    int i = blockIdx.x * 256 + threadIdx.x;
    if (i < n4) {
        float4 v = in[i];
        ushort4 o;
        o.x = f2bf(v.x); o.y = f2bf(v.y); o.z = f2bf(v.z); o.w = f2bf(v.w);
        out[i] = o;
    }
}

// ---------------------------------------------------------------------------
// LayerNorm (fp32 in) -> bf16 out.  One block (256 thr) per token, D=1024.
// ---------------------------------------------------------------------------
__global__ __launch_bounds__(256) void ln_cast(
    const float* __restrict__ x, const float* __restrict__ w,
    const float* __restrict__ b, unsigned short* __restrict__ out) {
    int tok = blockIdx.x;
    int t   = threadIdx.x;
    float4 v = ((const float4*)x)[tok * 256 + t];
    float s  = v.x + v.y + v.z + v.w;
    float ss = v.x * v.x + v.y * v.y + v.z * v.z + v.w * v.w;
    #pragma unroll
    for (int off = 32; off > 0; off >>= 1) {
        s  += __shfl_down(s, off);
        ss += __shfl_down(ss, off);
    }
    __shared__ float red[8];
    int wave = t >> 6;
    if ((t & 63) == 0) { red[wave * 2] = s; red[wave * 2 + 1] = ss; }
    __syncthreads();
    s  = red[0] + red[2] + red[4] + red[6];
    ss = red[1] + red[3] + red[5] + red[7];
    float mu  = s * (1.0f / 1024.0f);
    float var = ss * (1.0f / 1024.0f) - mu * mu;
    float rs  = rsqrtf(var + 1e-5f);
    float4 wv = ((const float4*)w)[t];
    float4 bv = ((const float4*)b)[t];
    ushort4 o;
    o.x = f2bf((v.x - mu) * rs * wv.x + bv.x);
    o.y = f2bf((v.y - mu) * rs * wv.y + bv.y);
    o.z = f2bf((v.z - mu) * rs * wv.z + bv.z);
    o.w = f2bf((v.w - mu) * rs * wv.w + bv.w);
    ((ushort4*)out)[tok * 256 + t] = o;
}

// ---------------------------------------------------------------------------
// Per-token head-attention: qkv row [3][16][64] bf16 -> out row [16*64] bf16.
// ---------------------------------------------------------------------------
__global__ __launch_bounds__(256) void attn_heads(
    const unsigned short* __restrict__ qkv, unsigned short* __restrict__ out) {
    __shared__ float sQ[1024], sK[1024], sV[1024];
    __shared__ float sS[256];
    int tok = blockIdx.x;
    int t   = threadIdx.x;
    const unsigned short* base = qkv + (size_t)tok * 3072;
    for (int i = t; i < 1024; i += 256) {
        sQ[i] = bf2f(base[i]);
        sK[i] = bf2f(base[1024 + i]);
        sV[i] = bf2f(base[2048 + i]);
    }
    __syncthreads();
    {
        int h = t >> 4, g = t & 15;
        float s = 0.0f;
        #pragma unroll
        for (int d = 0; d < 64; ++d) s += sQ[h * 64 + d] * sK[g * 64 + d];
        sS[h * 16 + g] = s * 0.125f;
    }
    __syncthreads();
    if (t < 16) {
        float mx = -1e30f;
        for (int g = 0; g < 16; ++g) mx = fmaxf(mx, sS[t * 16 + g]);
        float sum = 0.0f;
        for (int g = 0; g < 16; ++g) {
            float e = expf(sS[t * 16 + g] - mx);
            sS[t * 16 + g] = e;
            sum += e;
        }
        float inv = 1.0f / sum;
        for (int g = 0; g < 16; ++g) sS[t * 16 + g] *= inv;
    }
    __syncthreads();
    #pragma unroll
    for (int j = 0; j < 4; ++j) {
        int o = t + 256 * j;
        int h = o >> 6, d = o & 63;
        float s = 0.0f;
        #pragma unroll
        for (int g = 0; g < 16; ++g) s += sS[h * 16 + g] * sV[g * 64 + d];
        out[(size_t)tok * 1024 + o] = f2bf(s);
    }
}

// ---------------------------------------------------------------------------
// bf16 GEMM:  C[M,N] = A[M,K] . W[N,K]^T  (+ bias, + epilogue)
//   EPI 0: bf16 = acc+bias   EPI 1: f32 = acc+bias+resid (may alias Cout)
//   EPI 2: bf16 = gelu_tanh(acc+bias)
//
// 256x256 tile, BK=64, 512 threads = 8 waves (2M x 4N), per-wave 128x64
// output (acc[8][4] of 16x16x32 mfma).  LDS: 2 buffers x (A 4 panels +
// B 4 panels), panel = row-major 128x32 bf16, conflict-free chunk swizzle
// c ^ ((r>>1)&3), staged via pre-swizzled global source + linear
// global_load_lds dest.  128 KiB LDS -> 1 block/CU.
//
// Tile mapping (the round-6 lever): blocks dispatch round-robin to XCDs
// (bid&7).  Each XCD's 32 concurrent CUs form one 8m x 4n super-tile, so
// per K-tile its L2 misses 8 A-panels + 4 B-panels (shared by 4 / 8 blocks
// resp.) instead of 32 exclusive panel pairs.  Supers sequence m-fastest
// per XCD so the W panel stays L2-hot across supers.
//
// Schedule per K-tile (4 phases), double-buffered, counted vmcnt (never 0
// in main loop); raw s_barrier.  Tail K-tile compute-only with one
// vmcnt(0).  Requires M%256==0, N%256==0, K%64==0.
// ---------------------------------------------------------------------------
#define BM 256
#define BN 256

#define READ_A(kh) { _Pragma("unroll")                                        \
    for (int mf = 0; mf < 8; ++mf)                                            \
        a[mf] = *(const bf16x8*)(lA + bo + (kh)*8192 + pA + mf*512 + roA); }
#define READ_B(kh, i0, i1) {                                                  \
    b[i0] = *(const bf16x8*)(lB + bo + (kh)*8192 + pB + (i0)*512 + roB);      \
    b[i1] = *(const bf16x8*)(lB + bo + (kh)*8192 + pB + (i1)*512 + roB); }
#define MFMA_BLK(i0, i1) {                                                    \
    __builtin_amdgcn_s_setprio(1);                                            \
    _Pragma("unroll")                                                         \
    for (int mf = 0; mf < 8; ++mf) {                                          \
        acc[mf][i0] = mfma16(a[mf], b[i0], acc[mf][i0]);                      \
        acc[mf][i1] = mfma16(a[mf], b[i1], acc[mf][i1]);                      \
    }                                                                         \
    __builtin_amdgcn_s_setprio(0); }

template <int EPI>
__global__ __launch_bounds__(512, 2) void gemm_bf16(
    const unsigned short* __restrict__ A, const unsigned short* __restrict__ W,
    const float* __restrict__ bias, const float* resid, void* Cout,
    int M, int N, int K) {
    // [buf][panel kh*2+half][128*32]; 64 KiB each, 128 KiB total
    __shared__ __align__(16) unsigned short sA[2][4][4096];
    __shared__ __align__(16) unsigned short sB[2][4][4096];
    unsigned short* const lA = &sA[0][0][0];
    unsigned short* const lB = &sB[0][0][0];

    const int t    = threadIdx.x;
    const int lane = t & 63;
    const int w    = t >> 6;
    const int wm   = w >> 2;        // 0..1
    const int wn   = w & 3;         // 0..3

    // ---- tile mapping: XCD-concurrent 8m x 4n super-tiles ----
    const int gm = M >> 8, gn = N >> 8;
    const int nwg = gm * gn;
    int m0, n0;
    if (((gm & 7) == 0) && ((gn & 3) == 0) && ((nwg & 255) == 0)) {
        const int xcd = blockIdx.x & 7;     // HW round-robin XCD assignment
        const int j   = blockIdx.x >> 3;    // launch slot within this XCD
        const int pos = j & 31;             // CU slot within super-tile
        const int spx = nwg >> 8;           // supers per XCD
        const int sid = xcd * spx + (j >> 5);
        const int sgm = gm >> 3;            // supergrid m extent
        m0 = ((sid % sgm) * 8 + (pos >> 2)) << 8;
        n0 = ((sid / sgm) * 4 + (pos & 3)) << 8;
    } else {
        m0 = (blockIdx.x / gn) << 8;
        n0 = (blockIdx.x % gn) << 8;
    }

    // ---- staging source (per lane): wave w covers panel rows [w*16,w*16+16)
    // chunk cg = pos ^ ((row>>1)&3); with row = w*16 + (lane>>2) this is
    // (lane&3) ^ ((lane>>3)&3), independent of w (w*8 === 0 mod 4).
    const int srow = w * 16 + (lane >> 2);
    const int cg8  = ((lane & 3) ^ ((lane >> 3) & 3)) * 8;
    const unsigned short* gA0 = A + (size_t)(m0 +       srow) * K + cg8;
    const unsigned short* gA1 = A + (size_t)(m0 + 128 + srow) * K + cg8;
    const unsigned short* gB0 = W + (size_t)(n0 +       srow) * K + cg8;
    const unsigned short* gB1 = W + (size_t)(n0 + 128 + srow) * K + cg8;
    const int wst = w * 512;            // LDS dest offset within panel

    // ---- fragment read offsets (proven swizzle): retrieved chunk == fq
    const int fr   = lane & 15, fq = lane >> 4;
    const int csw8 = (fq ^ ((fr >> 1) & 3)) * 8;
    const int roA  = fr * 32 + csw8;                    // + mf*512, + kh*8192
    const int roB  = (wn & 1) * 2048 + fr * 32 + csw8;  // + nf*512, + kh*8192
    const int pA   = wm * 4096;                         // A panel: kh*2+wm
    const int pB   = (wn >> 1) * 4096;                  // B panel: kh*2+(wn>>1)

    f32x4 acc[8][4] = {};

    // ---- prologue: stage tile 0 into buf 0, kh0 panels first ----
    g2l16(gA0,      lA + 0 * 4096 + wst);   // kh0 mh0
    g2l16(gA1,      lA + 1 * 4096 + wst);   // kh0 mh1
    g2l16(gB0,      lB + 0 * 4096 + wst);   // kh0 nh0
    g2l16(gB1,      lB + 1 * 4096 + wst);   // kh0 nh1
    g2l16(gA0 + 32, lA + 2 * 4096 + wst);   // kh1 mh0
    g2l16(gA1 + 32, lA + 3 * 4096 + wst);   // kh1 mh1
    g2l16(gB0 + 32, lB + 2 * 4096 + wst);   // kh1 nh0
    g2l16(gB1 + 32, lB + 3 * 4096 + wst);   // kh1 nh1
    asm volatile("s_waitcnt vmcnt(4)" ::: "memory");   // kh0 panels landed
    __builtin_amdgcn_s_barrier();

    const int NT = K >> 6;
    for (int kt = 0; kt < NT - 1; ++kt) {
        const int bo = (kt & 1) << 14;      // compute buffer (ushort units)
        const int so = bo ^ 16384;          // stage buffer
        const size_t kg = (size_t)kt * 64 + 64;
        bf16x8 a[8], b[4];

        // ---- ph0
        READ_A(0); READ_B(0, 0, 1);
        g2l16(gA0 + kg, lA + so + wst);
        g2l16(gA1 + kg, lA + so + 4096 + wst);
        MFMA_BLK(0, 1);
        __builtin_amdgcn_s_barrier();
        // ---- ph1
        READ_B(0, 2, 3);
        g2l16(gB0 + kg, lB + so + wst);
        g2l16(gB1 + kg, lB + so + 4096 + wst);
        MFMA_BLK(2, 3);
        asm volatile("s_waitcnt vmcnt(4)" ::: "memory");  // kh1(cur) landed
        __builtin_amdgcn_s_barrier();
        // ---- ph2
        READ_A(1); READ_B(1, 0, 1);
        g2l16(gA0 + kg + 32, lA + so + 8192 + wst);
        g2l16(gA1 + kg + 32, lA + so + 8192 + 4096 + wst);
        MFMA_BLK(0, 1);
        __builtin_amdgcn_s_barrier();
        // ---- ph3
        READ_B(1, 2, 3);
        g2l16(gB0 + kg + 32, lB + so + 8192 + wst);
        g2l16(gB1 + kg + 32, lB + so + 8192 + 4096 + wst);
        MFMA_BLK(2, 3);
        asm volatile("s_waitcnt vmcnt(4)" ::: "memory");  // kh0(next) landed
        __builtin_amdgcn_s_barrier();
    }

    // ---- tail K-tile (no staging) ----
    {
        const int bo = ((NT - 1) & 1) << 14;
        bf16x8 a[8], b[4];
        READ_A(0); READ_B(0, 0, 1);
        MFMA_BLK(0, 1);
        __builtin_amdgcn_s_barrier();
        READ_B(0, 2, 3);
        MFMA_BLK(2, 3);
        asm volatile("s_waitcnt vmcnt(0)" ::: "memory");  // kh1 landed
        __builtin_amdgcn_s_barrier();
        READ_A(1); READ_B(1, 0, 1);
        MFMA_BLK(0, 1);
        READ_B(1, 2, 3);
        MFMA_BLK(2, 3);
    }

    // ---- epilogue: C/D layout col = lane&15, row = (lane>>4)*4 + e ----
    #pragma unroll
    for (int nf = 0; nf < 4; ++nf) {
        const int col = n0 + wn * 64 + nf * 16 + fr;
        const float bv = bias[col];
        #pragma unroll
        for (int mf = 0; mf < 8; ++mf) {
            const int rowb = m0 + wm * 128 + mf * 16 + fq * 4;
            #pragma unroll
            for (int e = 0; e < 4; ++e) {
                size_t idx = (size_t)(rowb + e) * N + col;
                float v = acc[mf][nf][e] + bv;
                if (EPI == 0) {
                    ((unsigned short*)Cout)[idx] = f2bf(v);
                } else if (EPI == 1) {
                    ((float*)Cout)[idx] = v + resid[idx];
                } else {
                    // tanh-form GELU: |err| < ~1e-3, far below bf16 noise
                    float s  = 0.7978845608f * (v + 0.044715f * v * v * v);
                    float e2 = __expf(2.0f * s);
                    float th = 1.0f - 2.0f / (e2 + 1.0f);
                    ((unsigned short*)Cout)[idx] = f2bf(0.5f * v * (1.0f + th));
                }
            }
        }
    }
}

#undef READ_A
#undef READ_B
#undef MFMA_BLK

// ---------------------------------------------------------------------------
// launch — chunked over token blocks sized to fit ws_size.
// ---------------------------------------------------------------------------
extern "C" void kernel_launch(void* const* d_in, const int* in_sizes, int n_in,
                              void* d_out, int out_size, void* d_ws, size_t ws_size,
                              hipStream_t stream) {
    const float* x      = (const float*)d_in[0];
    const float* qkv_w  = (const float*)d_in[1];
    const float* qkv_b  = (const float*)d_in[2];
    const float* proj_w = (const float*)d_in[3];
    const float* proj_b = (const float*)d_in[4];
    const float* ln1_w  = (const float*)d_in[5];
    const float* ln1_b  = (const float*)d_in[6];
    const float* ln2_w  = (const float*)d_in[7];
    const float* ln2_b  = (const float*)d_in[8];
    const float* mlp_w1 = (const float*)d_in[9];
    const float* mlp_b1 = (const float*)d_in[10];
    const float* mlp_w2 = (const float*)d_in[11];
    const float* mlp_b2 = (const float*)d_in[12];
    float* out = (float*)d_out;

    // persistent bf16 weights: 24 MB
    const size_t WB = 25165824;
    char* ws = (char*)d_ws;
    unsigned short* w_qkv  = (unsigned short*)(ws);              // [3072,1024]
    unsigned short* w_proj = (unsigned short*)(ws + 6291456);    // [1024,1024]
    unsigned short* w_m1   = (unsigned short*)(ws + 8388608);    // [4096,1024]
    unsigned short* w_m2   = (unsigned short*)(ws + 16777216);   // [1024,4096]

    // largest chunk T fitting:  WB + T*(2048 h + 2048 attn + 8192 qkv|m)
    int T = NTOK;
    while (T >= 256 && WB + (size_t)T * 12288 > ws_size) T >>= 1;
    if (T < 256) {
        hipMemcpyAsync(out, x, (size_t)NTOK * DMODEL * sizeof(float),
                       hipMemcpyDeviceToDevice, stream);
        return;
    }

    unsigned short* hbuf = (unsigned short*)(ws + WB);                     // T*2048 B
    unsigned short* abuf = (unsigned short*)(ws + WB + (size_t)T * 2048);  // T*2048 B
    unsigned short* qmbuf= (unsigned short*)(ws + WB + (size_t)T * 4096);  // T*8192 B

    cast_f32_bf16<<<3072, 256, 0, stream>>>((const float4*)qkv_w,  (ushort4*)w_qkv,  786432);
    cast_f32_bf16<<<1024, 256, 0, stream>>>((const float4*)proj_w, (ushort4*)w_proj, 262144);
    cast_f32_bf16<<<4096, 256, 0, stream>>>((const float4*)mlp_w1, (ushort4*)w_m1,   1048576);
    cast_f32_bf16<<<4096, 256, 0, stream>>>((const float4*)mlp_w2, (ushort4*)w_m2,   1048576);

    for (int tok0 = 0; tok0 < NTOK; tok0 += T) {
        const float* xc   = x   + (size_t)tok0 * DMODEL;
        float*       outc = out + (size_t)tok0 * DMODEL;
        const int my = T / BM;

        ln_cast<<<T, 256, 0, stream>>>(xc, ln1_w, ln1_b, hbuf);
        gemm_bf16<0><<<(3072 / BN) * my, 512, 0, stream>>>(
            hbuf, w_qkv, qkv_b, nullptr, qmbuf, T, 3072, 1024);
        attn_heads<<<T, 256, 0, stream>>>(qmbuf, abuf);
        gemm_bf16<1><<<(1024 / BN) * my, 512, 0, stream>>>(
            abuf, w_proj, proj_b, xc, (void*)outc, T, 1024, 1024);
        ln_cast<<<T, 256, 0, stream>>>(outc, ln2_w, ln2_b, hbuf);
        gemm_bf16<2><<<(4096 / BN) * my, 512, 0, stream>>>(
            hbuf, w_m1, mlp_b1, nullptr, qmbuf, T, 4096, 1024);
        gemm_bf16<1><<<(1024 / BN) * my, 512, 0, stream>>>(
            qmbuf, w_m2, mlp_b2, outc, (void*)outc, T, 1024, 4096);
    }
}

// Round 4
// 857.854 us; speedup vs baseline: 1.1928x; 1.0795x over previous
//
#include <hip/hip_runtime.h>
#include <cstdint>
#include <cmath>

// ---------------------------------------------------------------------------
// SimpleTransformerBlock on MI355X (gfx950)
// B=4, L=4096 -> 16384 tokens, D=1024, HEADS=16, HEAD_DIM=64
// Round 7 (resubmit; round-3 bench was an infra failure, no counters).
// Epilogue write coalescing.  rocprof r6: WRITE_SIZE ~313 MB vs 134 MB
// ideal (2.3x) at 1.6 TB/s -> write-bound, not fetch-bound.  Cause:
// nf-outer loop completes each 128B C-line (64 cols = one wave's 4 nf
// segments) only after a 32-store mf/e sweep; concurrent epilogues (4 MB
// dirty per XCD = L2 size) evict partial lines between installments ->
// multi-eviction + write-allocate refetch (also the remaining FETCH
// excess).  Fix: nf innermost -> line fully dirtied in 4 back-to-back
// stores.  Main loop / mapping / swizzle unchanged from round 6.
// ---------------------------------------------------------------------------

#define NTOK   16384
#define DMODEL 1024

typedef __bf16 bf16x8 __attribute__((ext_vector_type(8)));
typedef float  f32x4  __attribute__((ext_vector_type(4)));
typedef unsigned int __attribute__((address_space(1))) as1_uint;
typedef unsigned int __attribute__((address_space(3))) as3_uint;

__device__ __forceinline__ unsigned short f2bf(float f) {
    unsigned int u = __builtin_bit_cast(unsigned int, f);
    u += 0x7fffu + ((u >> 16) & 1u);          // round-to-nearest-even
    return (unsigned short)(u >> 16);
}
__device__ __forceinline__ float bf2f(unsigned short s) {
    unsigned int u = ((unsigned int)s) << 16;
    return __builtin_bit_cast(float, u);
}

// async global->LDS, 16 B per lane; LDS base wave-uniform (HW adds lane*16)
__device__ __forceinline__ void g2l16(const unsigned short* g, unsigned short* l) {
    __builtin_amdgcn_global_load_lds((const as1_uint*)g, (as3_uint*)l, 16, 0, 0);
}

__device__ __forceinline__ f32x4 mfma16(bf16x8 a, bf16x8 b, f32x4 c) {
    return __builtin_amdgcn_mfma_f32_16x16x32_bf16(a, b, c, 0, 0, 0);
}

// ---------------------------------------------------------------------------
// fp32 -> bf16 cast (weights)
// ---------------------------------------------------------------------------
__global__ __launch_bounds__(256) void cast_f32_bf16(
    const float4* __restrict__ in, ushort4* __restrict__ out, int n4) {
    int i = blockIdx.x * 256 + threadIdx.x;
    if (i < n4) {
        float4 v = in[i];
        ushort4 o;
        o.x = f2bf(v.x); o.y = f2bf(v.y); o.z = f2bf(v.z); o.w = f2bf(v.w);
        out[i] = o;
    }
}

// ---------------------------------------------------------------------------
// LayerNorm (fp32 in) -> bf16 out.  One block (256 thr) per token, D=1024.
// ---------------------------------------------------------------------------
__global__ __launch_bounds__(256) void ln_cast(
    const float* __restrict__ x, const float* __restrict__ w,
    const float* __restrict__ b, unsigned short* __restrict__ out) {
    int tok = blockIdx.x;
    int t   = threadIdx.x;
    float4 v = ((const float4*)x)[tok * 256 + t];
    float s  = v.x + v.y + v.z + v.w;
    float ss = v.x * v.x + v.y * v.y + v.z * v.z + v.w * v.w;
    #pragma unroll
    for (int off = 32; off > 0; off >>= 1) {
        s  += __shfl_down(s, off);
        ss += __shfl_down(ss, off);
    }
    __shared__ float red[8];
    int wave = t >> 6;
    if ((t & 63) == 0) { red[wave * 2] = s; red[wave * 2 + 1] = ss; }
    __syncthreads();
    s  = red[0] + red[2] + red[4] + red[6];
    ss = red[1] + red[3] + red[5] + red[7];
    float mu  = s * (1.0f / 1024.0f);
    float var = ss * (1.0f / 1024.0f) - mu * mu;
    float rs  = rsqrtf(var + 1e-5f);
    float4 wv = ((const float4*)w)[t];
    float4 bv = ((const float4*)b)[t];
    ushort4 o;
    o.x = f2bf((v.x - mu) * rs * wv.x + bv.x);
    o.y = f2bf((v.y - mu) * rs * wv.y + bv.y);
    o.z = f2bf((v.z - mu) * rs * wv.z + bv.z);
    o.w = f2bf((v.w - mu) * rs * wv.w + bv.w);
    ((ushort4*)out)[tok * 256 + t] = o;
}

// ---------------------------------------------------------------------------
// Per-token head-attention: qkv row [3][16][64] bf16 -> out row [16*64] bf16.
// ---------------------------------------------------------------------------
__global__ __launch_bounds__(256) void attn_heads(
    const unsigned short* __restrict__ qkv, unsigned short* __restrict__ out) {
    __shared__ float sQ[1024], sK[1024], sV[1024];
    __shared__ float sS[256];
    int tok = blockIdx.x;
    int t   = threadIdx.x;
    const unsigned short* base = qkv + (size_t)tok * 3072;
    for (int i = t; i < 1024; i += 256) {
        sQ[i] = bf2f(base[i]);
        sK[i] = bf2f(base[1024 + i]);
        sV[i] = bf2f(base[2048 + i]);
    }
    __syncthreads();
    {
        int h = t >> 4, g = t & 15;
        float s = 0.0f;
        #pragma unroll
        for (int d = 0; d < 64; ++d) s += sQ[h * 64 + d] * sK[g * 64 + d];
        sS[h * 16 + g] = s * 0.125f;
    }
    __syncthreads();
    if (t < 16) {
        float mx = -1e30f;
        for (int g = 0; g < 16; ++g) mx = fmaxf(mx, sS[t * 16 + g]);
        float sum = 0.0f;
        for (int g = 0; g < 16; ++g) {
            float e = expf(sS[t * 16 + g] - mx);
            sS[t * 16 + g] = e;
            sum += e;
        }
        float inv = 1.0f / sum;
        for (int g = 0; g < 16; ++g) sS[t * 16 + g] *= inv;
    }
    __syncthreads();
    #pragma unroll
    for (int j = 0; j < 4; ++j) {
        int o = t + 256 * j;
        int h = o >> 6, d = o & 63;
        float s = 0.0f;
        #pragma unroll
        for (int g = 0; g < 16; ++g) s += sS[h * 16 + g] * sV[g * 64 + d];
        out[(size_t)tok * 1024 + o] = f2bf(s);
    }
}

// ---------------------------------------------------------------------------
// bf16 GEMM:  C[M,N] = A[M,K] . W[N,K]^T  (+ bias, + epilogue)
//   EPI 0: bf16 = acc+bias   EPI 1: f32 = acc+bias+resid (may alias Cout)
//   EPI 2: bf16 = gelu_tanh(acc+bias)
//
// 256x256 tile, BK=64, 512 threads = 8 waves (2M x 4N), per-wave 128x64
// output (acc[8][4] of 16x16x32 mfma).  LDS: 2 buffers x (A 4 panels +
// B 4 panels), panel = row-major 128x32 bf16, conflict-free chunk swizzle
// c ^ ((r>>1)&3), staged via pre-swizzled global source + linear
// global_load_lds dest.  128 KiB LDS -> 1 block/CU.
//
// Tile mapping: blocks round-robin to XCDs (bid&7); each XCD's 32
// concurrent CUs form one 8m x 4n super-tile (L2-cooperative A/W reuse),
// supers sequenced m-fastest so the W panel stays L2-hot.
//
// Schedule per K-tile (4 phases), double-buffered, counted vmcnt (never 0
// in main loop); raw s_barrier.  Tail K-tile compute-only with one
// vmcnt(0).
//
// Epilogue: nf INNERMOST so each wave completes a full 128B C-line (its
// 64 cols) in 4 back-to-back stores -> single eviction, no write-allocate
// refetch.  Requires M%256==0, N%256==0, K%64==0.
// ---------------------------------------------------------------------------
#define BM 256
#define BN 256

#define READ_A(kh) { _Pragma("unroll")                                        \
    for (int mf = 0; mf < 8; ++mf)                                            \
        a[mf] = *(const bf16x8*)(lA + bo + (kh)*8192 + pA + mf*512 + roA); }
#define READ_B(kh, i0, i1) {                                                  \
    b[i0] = *(const bf16x8*)(lB + bo + (kh)*8192 + pB + (i0)*512 + roB);      \
    b[i1] = *(const bf16x8*)(lB + bo + (kh)*8192 + pB + (i1)*512 + roB); }
#define MFMA_BLK(i0, i1) {                                                    \
    __builtin_amdgcn_s_setprio(1);                                            \
    _Pragma("unroll")                                                         \
    for (int mf = 0; mf < 8; ++mf) {                                          \
        acc[mf][i0] = mfma16(a[mf], b[i0], acc[mf][i0]);                      \
        acc[mf][i1] = mfma16(a[mf], b[i1], acc[mf][i1]);                      \
    }                                                                         \
    __builtin_amdgcn_s_setprio(0); }

template <int EPI>
__global__ __launch_bounds__(512, 2) void gemm_bf16(
    const unsigned short* __restrict__ A, const unsigned short* __restrict__ W,
    const float* __restrict__ bias, const float* resid, void* Cout,
    int M, int N, int K) {
    // [buf][panel kh*2+half][128*32]; 64 KiB each, 128 KiB total
    __shared__ __align__(16) unsigned short sA[2][4][4096];
    __shared__ __align__(16) unsigned short sB[2][4][4096];
    unsigned short* const lA = &sA[0][0][0];
    unsigned short* const lB = &sB[0][0][0];

    const int t    = threadIdx.x;
    const int lane = t & 63;
    const int w    = t >> 6;
    const int wm   = w >> 2;        // 0..1
    const int wn   = w & 3;         // 0..3

    // ---- tile mapping: XCD-concurrent 8m x 4n super-tiles ----
    const int gm = M >> 8, gn = N >> 8;
    const int nwg = gm * gn;
    int m0, n0;
    if (((gm & 7) == 0) && ((gn & 3) == 0) && ((nwg & 255) == 0)) {
        const int xcd = blockIdx.x & 7;     // HW round-robin XCD assignment
        const int j   = blockIdx.x >> 3;    // launch slot within this XCD
        const int pos = j & 31;             // CU slot within super-tile
        const int spx = nwg >> 8;           // supers per XCD
        const int sid = xcd * spx + (j >> 5);
        const int sgm = gm >> 3;            // supergrid m extent
        m0 = ((sid % sgm) * 8 + (pos >> 2)) << 8;
        n0 = ((sid / sgm) * 4 + (pos & 3)) << 8;
    } else {
        m0 = (blockIdx.x / gn) << 8;
        n0 = (blockIdx.x % gn) << 8;
    }

    // ---- staging source (per lane): wave w covers panel rows [w*16,w*16+16)
    // chunk cg = pos ^ ((row>>1)&3); with row = w*16 + (lane>>2) this is
    // (lane&3) ^ ((lane>>3)&3), independent of w (w*8 === 0 mod 4).
    const int srow = w * 16 + (lane >> 2);
    const int cg8  = ((lane & 3) ^ ((lane >> 3) & 3)) * 8;
    const unsigned short* gA0 = A + (size_t)(m0 +       srow) * K + cg8;
    const unsigned short* gA1 = A + (size_t)(m0 + 128 + srow) * K + cg8;
    const unsigned short* gB0 = W + (size_t)(n0 +       srow) * K + cg8;
    const unsigned short* gB1 = W + (size_t)(n0 + 128 + srow) * K + cg8;
    const int wst = w * 512;            // LDS dest offset within panel

    // ---- fragment read offsets (proven swizzle): retrieved chunk == fq
    const int fr   = lane & 15, fq = lane >> 4;
    const int csw8 = (fq ^ ((fr >> 1) & 3)) * 8;
    const int roA  = fr * 32 + csw8;                    // + mf*512, + kh*8192
    const int roB  = (wn & 1) * 2048 + fr * 32 + csw8;  // + nf*512, + kh*8192
    const int pA   = wm * 4096;                         // A panel: kh*2+wm
    const int pB   = (wn >> 1) * 4096;                  // B panel: kh*2+(wn>>1)

    f32x4 acc[8][4] = {};

    // ---- prologue: stage tile 0 into buf 0, kh0 panels first ----
    g2l16(gA0,      lA + 0 * 4096 + wst);   // kh0 mh0
    g2l16(gA1,      lA + 1 * 4096 + wst);   // kh0 mh1
    g2l16(gB0,      lB + 0 * 4096 + wst);   // kh0 nh0
    g2l16(gB1,      lB + 1 * 4096 + wst);   // kh0 nh1
    g2l16(gA0 + 32, lA + 2 * 4096 + wst);   // kh1 mh0
    g2l16(gA1 + 32, lA + 3 * 4096 + wst);   // kh1 mh1
    g2l16(gB0 + 32, lB + 2 * 4096 + wst);   // kh1 nh0
    g2l16(gB1 + 32, lB + 3 * 4096 + wst);   // kh1 nh1
    asm volatile("s_waitcnt vmcnt(4)" ::: "memory");   // kh0 panels landed
    __builtin_amdgcn_s_barrier();

    const int NT = K >> 6;
    for (int kt = 0; kt < NT - 1; ++kt) {
        const int bo = (kt & 1) << 14;      // compute buffer (ushort units)
        const int so = bo ^ 16384;          // stage buffer
        const size_t kg = (size_t)kt * 64 + 64;
        bf16x8 a[8], b[4];

        // ---- ph0
        READ_A(0); READ_B(0, 0, 1);
        g2l16(gA0 + kg, lA + so + wst);
        g2l16(gA1 + kg, lA + so + 4096 + wst);
        MFMA_BLK(0, 1);
        __builtin_amdgcn_s_barrier();
        // ---- ph1
        READ_B(0, 2, 3);
        g2l16(gB0 + kg, lB + so + wst);
        g2l16(gB1 + kg, lB + so + 4096 + wst);
        MFMA_BLK(2, 3);
        asm volatile("s_waitcnt vmcnt(4)" ::: "memory");  // kh1(cur) landed
        __builtin_amdgcn_s_barrier();
        // ---- ph2
        READ_A(1); READ_B(1, 0, 1);
        g2l16(gA0 + kg + 32, lA + so + 8192 + wst);
        g2l16(gA1 + kg + 32, lA + so + 8192 + 4096 + wst);
        MFMA_BLK(0, 1);
        __builtin_amdgcn_s_barrier();
        // ---- ph3
        READ_B(1, 2, 3);
        g2l16(gB0 + kg + 32, lB + so + 8192 + wst);
        g2l16(gB1 + kg + 32, lB + so + 8192 + 4096 + wst);
        MFMA_BLK(2, 3);
        asm volatile("s_waitcnt vmcnt(4)" ::: "memory");  // kh0(next) landed
        __builtin_amdgcn_s_barrier();
    }

    // ---- tail K-tile (no staging) ----
    {
        const int bo = ((NT - 1) & 1) << 14;
        bf16x8 a[8], b[4];
        READ_A(0); READ_B(0, 0, 1);
        MFMA_BLK(0, 1);
        __builtin_amdgcn_s_barrier();
        READ_B(0, 2, 3);
        MFMA_BLK(2, 3);
        asm volatile("s_waitcnt vmcnt(0)" ::: "memory");  // kh1 landed
        __builtin_amdgcn_s_barrier();
        READ_A(1); READ_B(1, 0, 1);
        MFMA_BLK(0, 1);
        READ_B(1, 2, 3);
        MFMA_BLK(2, 3);
    }

    // ---- epilogue: C/D layout col = lane&15, row = (lane>>4)*4 + e ----
    // nf innermost: wave's 4 x 32B segments of each 128B line issue
    // back-to-back -> full-line dirty, single eviction, no RMW refetch.
    float bv[4];
    #pragma unroll
    for (int nf = 0; nf < 4; ++nf) bv[nf] = bias[n0 + wn * 64 + nf * 16 + fr];
    #pragma unroll
    for (int mf = 0; mf < 8; ++mf) {
        #pragma unroll
        for (int e = 0; e < 4; ++e) {
            const int row = m0 + wm * 128 + mf * 16 + fq * 4 + e;
            const size_t rbase = (size_t)row * N + n0 + wn * 64 + fr;
            #pragma unroll
            for (int nf = 0; nf < 4; ++nf) {
                const size_t idx = rbase + nf * 16;
                float v = acc[mf][nf][e] + bv[nf];
                if (EPI == 0) {
                    ((unsigned short*)Cout)[idx] = f2bf(v);
                } else if (EPI == 1) {
                    ((float*)Cout)[idx] = v + resid[idx];
                } else {
                    // tanh-form GELU: |err| < ~1e-3, far below bf16 noise
                    float s  = 0.7978845608f * (v + 0.044715f * v * v * v);
                    float e2 = __expf(2.0f * s);
                    float th = 1.0f - 2.0f / (e2 + 1.0f);
                    ((unsigned short*)Cout)[idx] = f2bf(0.5f * v * (1.0f + th));
                }
            }
        }
    }
}

#undef READ_A
#undef READ_B
#undef MFMA_BLK

// ---------------------------------------------------------------------------
// launch — chunked over token blocks sized to fit ws_size.
// ---------------------------------------------------------------------------
extern "C" void kernel_launch(void* const* d_in, const int* in_sizes, int n_in,
                              void* d_out, int out_size, void* d_ws, size_t ws_size,
                              hipStream_t stream) {
    const float* x      = (const float*)d_in[0];
    const float* qkv_w  = (const float*)d_in[1];
    const float* qkv_b  = (const float*)d_in[2];
    const float* proj_w = (const float*)d_in[3];
    const float* proj_b = (const float*)d_in[4];
    const float* ln1_w  = (const float*)d_in[5];
    const float* ln1_b  = (const float*)d_in[6];
    const float* ln2_w  = (const float*)d_in[7];
    const float* ln2_b  = (const float*)d_in[8];
    const float* mlp_w1 = (const float*)d_in[9];
    const float* mlp_b1 = (const float*)d_in[10];
    const float* mlp_w2 = (const float*)d_in[11];
    const float* mlp_b2 = (const float*)d_in[12];
    float* out = (float*)d_out;

    // persistent bf16 weights: 24 MB
    const size_t WB = 25165824;
    char* ws = (char*)d_ws;
    unsigned short* w_qkv  = (unsigned short*)(ws);              // [3072,1024]
    unsigned short* w_proj = (unsigned short*)(ws + 6291456);    // [1024,1024]
    unsigned short* w_m1   = (unsigned short*)(ws + 8388608);    // [4096,1024]
    unsigned short* w_m2   = (unsigned short*)(ws + 16777216);   // [1024,4096]

    // largest chunk T fitting:  WB + T*(2048 h + 2048 attn + 8192 qkv|m)
    int T = NTOK;
    while (T >= 256 && WB + (size_t)T * 12288 > ws_size) T >>= 1;
    if (T < 256) {
        hipMemcpyAsync(out, x, (size_t)NTOK * DMODEL * sizeof(float),
                       hipMemcpyDeviceToDevice, stream);
        return;
    }

    unsigned short* hbuf = (unsigned short*)(ws + WB);                     // T*2048 B
    unsigned short* abuf = (unsigned short*)(ws + WB + (size_t)T * 2048);  // T*2048 B
    unsigned short* qmbuf= (unsigned short*)(ws + WB + (size_t)T * 4096);  // T*8192 B

    cast_f32_bf16<<<3072, 256, 0, stream>>>((const float4*)qkv_w,  (ushort4*)w_qkv,  786432);
    cast_f32_bf16<<<1024, 256, 0, stream>>>((const float4*)proj_w, (ushort4*)w_proj, 262144);
    cast_f32_bf16<<<4096, 256, 0, stream>>>((const float4*)mlp_w1, (ushort4*)w_m1,   1048576);
    cast_f32_bf16<<<4096, 256, 0, stream>>>((const float4*)mlp_w2, (ushort4*)w_m2,   1048576);

    for (int tok0 = 0; tok0 < NTOK; tok0 += T) {
        const float* xc   = x   + (size_t)tok0 * DMODEL;
        float*       outc = out + (size_t)tok0 * DMODEL;
        const int my = T / BM;

        ln_cast<<<T, 256, 0, stream>>>(xc, ln1_w, ln1_b, hbuf);
        gemm_bf16<0><<<(3072 / BN) * my, 512, 0, stream>>>(
            hbuf, w_qkv, qkv_b, nullptr, qmbuf, T, 3072, 1024);
        attn_heads<<<T, 256, 0, stream>>>(qmbuf, abuf);
        gemm_bf16<1><<<(1024 / BN) * my, 512, 0, stream>>>(
            abuf, w_proj, proj_b, xc, (void*)outc, T, 1024, 1024);
        ln_cast<<<T, 256, 0, stream>>>(outc, ln2_w, ln2_b, hbuf);
        gemm_bf16<2><<<(4096 / BN) * my, 512, 0, stream>>>(
            hbuf, w_m1, mlp_b1, nullptr, qmbuf, T, 4096, 1024);
        gemm_bf16<1><<<(1024 / BN) * my, 512, 0, stream>>>(
            qmbuf, w_m2, mlp_b2, outc, (void*)outc, T, 1024, 4096);
    }
}